// Round 14
// baseline (510.371 us; speedup 1.0000x reference)
//
#include <hip/hip_runtime.h>
#include <hip/hip_bf16.h>
#include <hip/hip_fp16.h>

// Problem constants (match reference)
#define NN     20000
#define ERAW   320000
#define ETOT   (ERAW + NN)   // 340000 with self loops
#define F_IN   50
#define HID    64
#define HEADS  8
#define WIDTH  512           // HID*HEADS
#define NCLS   121
#define NCLS_P 128           // padded cols for layer-3 MFMA GEMM

typedef __attribute__((ext_vector_type(8))) __bf16 bf16x8;
typedef __attribute__((ext_vector_type(4))) float floatx4;

// ---------------- fp32 -> bf16 split helpers --------------------------------
__device__ __forceinline__ unsigned short f32_to_bf16_rn(float f) {
  unsigned u = __float_as_uint(f);
  unsigned r = u + 0x7fffu + ((u >> 16) & 1u);
  return (unsigned short)(r >> 16);
}
__device__ __forceinline__ void split_one(float f, unsigned short& h,
                                          unsigned short& l) {
  h = f32_to_bf16_rn(f);
  float fh = __uint_as_float(((unsigned)h) << 16);
  l = f32_to_bf16_rn(f - fh);
}

__device__ __forceinline__ float2 u2f2(unsigned u) {
  __half2 hv = *reinterpret_cast<__half2*>(&u);
  return __half22float2(hv);
}

// W [K][M] fp32 -> Bt hi/lo [Mp][K] bf16 ushort (rows m>=M zero-padded)
__global__ __launch_bounds__(256) void transpose_split(
    const float* __restrict__ W, unsigned short* __restrict__ thi,
    unsigned short* __restrict__ tlo, int K, int M, int Mp) {
  __shared__ float t[32][33];
  int k0 = blockIdx.x * 32, m0 = blockIdx.y * 32;
  int tx = threadIdx.x & 31, ty = threadIdx.x >> 5;  // 32 x 8
  #pragma unroll
  for (int r = 0; r < 4; ++r) {
    int k = k0 + ty + r * 8, m = m0 + tx;
    float v = 0.f;
    if (k < K && m < M) v = W[(size_t)k * M + m];
    t[ty + r * 8][tx] = v;
  }
  __syncthreads();
  #pragma unroll
  for (int r = 0; r < 4; ++r) {
    int m = m0 + ty + r * 8, k = k0 + tx;
    if (m < Mp && k < K) {
      unsigned short h, l;
      split_one(t[tx][ty + r * 8], h, l);
      thi[(size_t)m * K + k] = h;
      tlo[(size_t)m * K + k] = l;
    }
  }
}

// Per-head W1 transposed split: w1h[hd][col(64)][k(64)], k>=50 zero.
__global__ __launch_bounds__(256) void build_w1h_t(
    const float* __restrict__ W1, unsigned short* __restrict__ thi,
    unsigned short* __restrict__ tlo) {
  int idx = blockIdx.x * blockDim.x + threadIdx.x;
  if (idx >= HEADS * HID * HID) return;
  int hd = idx >> 12, rem = idx & 4095;
  int col = rem >> 6, k = rem & 63;
  float v = (k < F_IN) ? W1[(size_t)k * WIDTH + hd * HID + col] : 0.f;
  unsigned short h, l;
  split_one(v, h, l);
  thi[idx] = h;
  tlo[idx] = l;
}

// x [NN,50] fp32 -> fp16 (L2-resident 2 MB gather target for agg_x_sm)
__global__ __launch_bounds__(256) void x_to_f16(
    const float* __restrict__ x, __half* __restrict__ x16) {
  int i = blockIdx.x * blockDim.x + threadIdx.x;
  if (i < NN * F_IN) x16[i] = __float2half(x[i]);
}

// ---- split-bf16 MFMA GEMM: C16[N,M] = fp16(A[N,K] @ B[K,M]) ----------------
// Fused attention-logit epilogue: al_s[row] += sum_col v*a_src[col] (atomic),
// same for al_d. fp32 C is never materialized.
__global__ __launch_bounds__(256) void gemm_mfma_split(
    const unsigned short* __restrict__ Ahi, const unsigned short* __restrict__ Alo,
    const unsigned short* __restrict__ Bthi, const unsigned short* __restrict__ Btlo,
    __half* __restrict__ C16, const float* __restrict__ a_src,
    const float* __restrict__ a_dst, float* __restrict__ al_s,
    float* __restrict__ al_d, int N, int K, int M) {
  __shared__ unsigned short sAhi[4096], sAlo[4096], sBhi[4096], sBlo[4096];
  const int tid = threadIdx.x;
  const int wave = tid >> 6, lane = tid & 63;
  const int wr = wave >> 1, wc = wave & 1;
  const int r0 = blockIdx.y * 128;
  const int c0 = blockIdx.x * 128;
  const int lkg = lane >> 4;
  const int lmn = lane & 15;

  const int skg = tid & 3;
  const int srow = tid >> 2;
  int ra0 = r0 + srow;        if (ra0 > NN - 1) ra0 = NN - 1;
  int ra1 = r0 + srow + 64;   if (ra1 > NN - 1) ra1 = NN - 1;
  const unsigned short* gAhi0 = Ahi + (size_t)ra0 * K + skg * 8;
  const unsigned short* gAhi1 = Ahi + (size_t)ra1 * K + skg * 8;
  const unsigned short* gAlo0 = Alo + (size_t)ra0 * K + skg * 8;
  const unsigned short* gAlo1 = Alo + (size_t)ra1 * K + skg * 8;
  const unsigned short* gBhi0 = Bthi + (size_t)(c0 + srow) * K + skg * 8;
  const unsigned short* gBhi1 = Bthi + (size_t)(c0 + srow + 64) * K + skg * 8;
  const unsigned short* gBlo0 = Btlo + (size_t)(c0 + srow) * K + skg * 8;
  const unsigned short* gBlo1 = Btlo + (size_t)(c0 + srow + 64) * K + skg * 8;

  floatx4 acc[4][4] = {};

  uint4 a0, a1, a2, a3, b0, b1, b2, b3;
  auto gload = [&](int kk) {
    a0 = *(const uint4*)(gAhi0 + kk);
    a1 = *(const uint4*)(gAhi1 + kk);
    a2 = *(const uint4*)(gAlo0 + kk);
    a3 = *(const uint4*)(gAlo1 + kk);
    b0 = *(const uint4*)(gBhi0 + kk);
    b1 = *(const uint4*)(gBhi1 + kk);
    b2 = *(const uint4*)(gBlo0 + kk);
    b3 = *(const uint4*)(gBlo1 + kk);
  };
  gload(0);

  const int w0 = (skg * 128 + srow) * 8;
  const int w1 = (skg * 128 + srow + 64) * 8;

  for (int k0 = 0; k0 < K; k0 += 32) {
    __syncthreads();
    *(uint4*)(sAhi + w0) = a0;
    *(uint4*)(sAhi + w1) = a1;
    *(uint4*)(sAlo + w0) = a2;
    *(uint4*)(sAlo + w1) = a3;
    *(uint4*)(sBhi + w0) = b0;
    *(uint4*)(sBhi + w1) = b1;
    *(uint4*)(sBlo + w0) = b2;
    *(uint4*)(sBlo + w1) = b3;
    __syncthreads();
    if (k0 + 32 < K) gload(k0 + 32);

    bf16x8 fAhi[4], fAlo[4], fBhi[4], fBlo[4];
    #pragma unroll
    for (int mi = 0; mi < 4; ++mi) {
      int m = wr * 64 + mi * 16 + lmn;
      fAhi[mi] = *(const bf16x8*)(sAhi + (lkg * 128 + m) * 8);
      fAlo[mi] = *(const bf16x8*)(sAlo + (lkg * 128 + m) * 8);
    }
    #pragma unroll
    for (int ni = 0; ni < 4; ++ni) {
      int n = wc * 64 + ni * 16 + lmn;
      fBhi[ni] = *(const bf16x8*)(sBhi + (lkg * 128 + n) * 8);
      fBlo[ni] = *(const bf16x8*)(sBlo + (lkg * 128 + n) * 8);
    }
    #pragma unroll
    for (int mi = 0; mi < 4; ++mi)
      #pragma unroll
      for (int ni = 0; ni < 4; ++ni) {
        acc[mi][ni] = __builtin_amdgcn_mfma_f32_16x16x32_bf16(
            fAhi[mi], fBhi[ni], acc[mi][ni], 0, 0, 0);
        acc[mi][ni] = __builtin_amdgcn_mfma_f32_16x16x32_bf16(
            fAhi[mi], fBlo[ni], acc[mi][ni], 0, 0, 0);
        acc[mi][ni] = __builtin_amdgcn_mfma_f32_16x16x32_bf16(
            fAlo[mi], fBhi[ni], acc[mi][ni], 0, 0, 0);
      }
  }

  // epilogue: fp16 store + fused per-row logit reduction.
  // acc[mi][ni][r] -> row r0+wr*64+mi*16+(lane>>4)*4+r, col c0+wc*64+ni*16+lmn
  #pragma unroll
  for (int mi = 0; mi < 4; ++mi) {
    #pragma unroll
    for (int r = 0; r < 4; ++r) {
      int grow = r0 + wr * 64 + mi * 16 + (lane >> 4) * 4 + r;
      float asum = 0.f, adsum = 0.f;
      #pragma unroll
      for (int ni = 0; ni < 4; ++ni) {
        int gcol = c0 + wc * 64 + ni * 16 + lmn;
        float v = acc[mi][ni][r];
        if (gcol < M) {
          if (grow < N) C16[(size_t)grow * M + gcol] = __float2half(v);
          asum += v * a_src[gcol];
          adsum += v * a_dst[gcol];
        }
      }
      // reduce over the 16 lanes of this row-group (cols)
      #pragma unroll
      for (int o = 8; o; o >>= 1) {
        asum += __shfl_xor(asum, o);
        adsum += __shfl_xor(adsum, o);
      }
      if (grow < N && lmn == 0) {
        atomicAdd(&al_s[grow], asum);
        atomicAdd(&al_d[grow], adsum);
      }
    }
  }
}

// ---- batched per-head L1 GEMM: C[n,hd*64+c] = elu(A[n,hd*64+:64]@W1h + b1) -
__global__ __launch_bounds__(256) void gemm_l1_heads(
    const unsigned short* __restrict__ Ahi, const unsigned short* __restrict__ Alo,
    const unsigned short* __restrict__ Bthi, const unsigned short* __restrict__ Btlo,
    unsigned short* __restrict__ outHi, unsigned short* __restrict__ outLo,
    const float* __restrict__ bias) {
  __shared__ unsigned short sAhi[8192], sAlo[8192], sBhi[4096], sBlo[4096];
  const int tid = threadIdx.x;
  const int wave = tid >> 6, lane = tid & 63;
  const int r0 = blockIdx.x * 128;
  const int hd = blockIdx.y;
  const int lkg = lane >> 4, lmn = lane & 15;

  #pragma unroll
  for (int t = 0; t < 4; ++t) {
    int cid = tid + t * 256;
    int row = cid >> 3, c = cid & 7;
    int gr = r0 + row; if (gr > NN - 1) gr = NN - 1;
    const size_t goff = (size_t)gr * WIDTH + hd * HID + c * 8;
    int loff = (((c >> 2) * 4 + (c & 3)) * 128 + row) * 8;
    *(uint4*)(sAhi + loff) = *(const uint4*)(Ahi + goff);
    *(uint4*)(sAlo + loff) = *(const uint4*)(Alo + goff);
  }
  #pragma unroll
  for (int t = 0; t < 2; ++t) {
    int cid = tid + t * 256;
    int col = cid >> 3, c = cid & 7;
    const size_t goff = (size_t)(hd * HID + col) * HID + c * 8;
    int loff = (((c >> 2) * 4 + (c & 3)) * 64 + col) * 8;
    *(uint4*)(sBhi + loff) = *(const uint4*)(Bthi + goff);
    *(uint4*)(sBlo + loff) = *(const uint4*)(Btlo + goff);
  }
  __syncthreads();

  floatx4 acc[2][4] = {};
  #pragma unroll
  for (int ks = 0; ks < 2; ++ks) {
    bf16x8 fAhi[2], fAlo[2], fBhi[4], fBlo[4];
    #pragma unroll
    for (int mi = 0; mi < 2; ++mi) {
      int m = wave * 32 + mi * 16 + lmn;
      int off = ((ks * 4 + lkg) * 128 + m) * 8;
      fAhi[mi] = *(const bf16x8*)(sAhi + off);
      fAlo[mi] = *(const bf16x8*)(sAlo + off);
    }
    #pragma unroll
    for (int ni = 0; ni < 4; ++ni) {
      int n = ni * 16 + lmn;
      int off = ((ks * 4 + lkg) * 64 + n) * 8;
      fBhi[ni] = *(const bf16x8*)(sBhi + off);
      fBlo[ni] = *(const bf16x8*)(sBlo + off);
    }
    #pragma unroll
    for (int mi = 0; mi < 2; ++mi)
      #pragma unroll
      for (int ni = 0; ni < 4; ++ni) {
        acc[mi][ni] = __builtin_amdgcn_mfma_f32_16x16x32_bf16(
            fAhi[mi], fBhi[ni], acc[mi][ni], 0, 0, 0);
        acc[mi][ni] = __builtin_amdgcn_mfma_f32_16x16x32_bf16(
            fAhi[mi], fBlo[ni], acc[mi][ni], 0, 0, 0);
        acc[mi][ni] = __builtin_amdgcn_mfma_f32_16x16x32_bf16(
            fAlo[mi], fBhi[ni], acc[mi][ni], 0, 0, 0);
      }
  }

  #pragma unroll
  for (int mi = 0; mi < 2; ++mi) {
    #pragma unroll
    for (int r = 0; r < 4; ++r) {
      int grow = r0 + wave * 32 + mi * 16 + (lane >> 4) * 4 + r;
      if (grow >= NN) continue;
      #pragma unroll
      for (int ni = 0; ni < 4; ++ni) {
        int gcol = hd * HID + ni * 16 + lmn;
        float v = acc[mi][ni][r] + bias[gcol];
        v = (v > 0.f) ? v : (__expf(v) - 1.0f);
        unsigned short hh, ll;
        split_one(v, hh, ll);
        outHi[(size_t)grow * WIDTH + gcol] = hh;
        outLo[(size_t)grow * WIDTH + gcol] = ll;
      }
    }
  }
}

// ---------------- layer-1 folded attention weights --------------------------
__global__ __launch_bounds__(256) void fold_w1a(
    const float* __restrict__ W1, const float* __restrict__ a1s,
    const float* __restrict__ a1d, float* __restrict__ w1as,
    float* __restrict__ w1ad) {
  int idx = blockIdx.x * blockDim.x + threadIdx.x;
  if (idx >= 2 * F_IN * HEADS) return;
  int which = idx >= F_IN * HEADS;
  int r = which ? idx - F_IN * HEADS : idx;
  int k = r >> 3, h = r & 7;
  const float* a = which ? a1d : a1s;
  float s = 0.f;
  for (int c = 0; c < HID; ++c) s += W1[(size_t)k * WIDTH + h * HID + c] * a[h * HID + c];
  (which ? w1ad : w1as)[r] = s;
}

// al1[n,h] = sum_k x[n,k] * w1a[k,h]   (one wave per node)
__global__ __launch_bounds__(256) void al1_kernel(
    const float* __restrict__ x, const float* __restrict__ w1as,
    const float* __restrict__ w1ad, float* __restrict__ al_s,
    float* __restrict__ al_d) {
  int n = (blockIdx.x * blockDim.x + threadIdx.x) >> 6;
  int lane = threadIdx.x & 63;
  if (n >= NN) return;
  float xv = (lane < F_IN) ? x[(size_t)n * F_IN + lane] : 0.f;
  float ws[HEADS], wd[HEADS];
  #pragma unroll
  for (int h = 0; h < HEADS; ++h) {
    ws[h] = (lane < F_IN) ? w1as[lane * HEADS + h] : 0.f;
    wd[h] = (lane < F_IN) ? w1ad[lane * HEADS + h] : 0.f;
  }
  #pragma unroll
  for (int h = 0; h < HEADS; ++h) {
    float ss = xv * ws[h], sd = xv * wd[h];
    #pragma unroll
    for (int o = 32; o; o >>= 1) {
      ss += __shfl_xor(ss, o);
      sd += __shfl_xor(sd, o);
    }
    if (lane == 0) {
      al_s[n * HEADS + h] = ss;
      al_d[n * HEADS + h] = sd;
    }
  }
}

// ---------------- CSR build (once; shared by all layers) --------------------
__global__ __launch_bounds__(256) void count_deg(
    const int* __restrict__ edst, int* __restrict__ deg) {
  int e = blockIdx.x * blockDim.x + threadIdx.x;
  if (e >= ETOT) return;
  int d = (e < ERAW) ? edst[e] : (e - ERAW);
  atomicAdd(&deg[d], 1);
}

__global__ __launch_bounds__(256) void scan_deg(
    const int* __restrict__ deg, int* __restrict__ rowptr) {
  __shared__ int part[256];
  const int t = threadIdx.x;
  const int CHUNK = (NN + 255) / 256;
  int lo = t * CHUNK, hi = min(lo + CHUNK, NN);
  int s = 0;
  for (int i = lo; i < hi; ++i) s += deg[i];
  part[t] = s;
  __syncthreads();
  for (int off = 1; off < 256; off <<= 1) {
    int v = (t >= off) ? part[t - off] : 0;
    __syncthreads();
    part[t] += v;
    __syncthreads();
  }
  int base = (t == 0) ? 0 : part[t - 1];
  for (int i = lo; i < hi; ++i) {
    rowptr[i] = base;
    base += deg[i];
  }
  if (t == 255) rowptr[NN] = part[255];
}

__global__ __launch_bounds__(256) void scatter_csr(
    const int* __restrict__ esrc, const int* __restrict__ edst,
    const int* __restrict__ rowptr, int* __restrict__ cnt,
    int* __restrict__ csrc) {
  int e = blockIdx.x * blockDim.x + threadIdx.x;
  if (e >= ETOT) return;
  int s, d;
  if (e < ERAW) { s = esrc[e]; d = edst[e]; }
  else          { s = e - ERAW; d = e - ERAW; }
  int pos = rowptr[d] + atomicAdd(&cnt[d], 1);
  csrc[pos] = s;
}

// ---- layer-1 fused SINGLE-PASS softmax+aggregate (self-loop-logit shift) --
__global__ __launch_bounds__(256) void agg_x_sm(
    const int* __restrict__ rowptr, const int* __restrict__ csrc,
    const float* __restrict__ al_s, const float* __restrict__ al_d,
    const __half* __restrict__ x16, unsigned short* __restrict__ outHi,
    unsigned short* __restrict__ outLo) {
  const int w = threadIdx.x >> 6, lane = threadIdx.x & 63;
  const int d = blockIdx.x * 4 + w;
  if (d >= NN) return;
  const int r0 = rowptr[d], r1 = rowptr[d + 1];
  const int mh = lane & 7;  // this lane computes alpha for head mh
  const float ald_my = al_d[d * HEADS + mh];
  float m_my = al_s[d * HEADS + mh] + ald_my;
  m_my = (m_my > 0.f) ? m_my : 0.2f * m_my;

  float z_my = 0.f;
  float acc[HEADS];
  #pragma unroll
  for (int hh = 0; hh < HEADS; ++hh) acc[hh] = 0.f;
  for (int p = r0; p < r1; ++p) {
    int s = csrc[p];
    float v = al_s[s * HEADS + mh] + ald_my;
    v = (v > 0.f) ? v : 0.2f * v;
    float a = __expf(v - m_my);
    z_my += a;
    float xv = (lane < F_IN) ? __half2float(x16[(size_t)s * F_IN + lane])
                             : 0.f;
    #pragma unroll
    for (int hh = 0; hh < HEADS; ++hh) acc[hh] += __shfl(a, hh, 8) * xv;
  }
  #pragma unroll
  for (int hh = 0; hh < HEADS; ++hh) {
    float zh = __shfl(z_my, hh, 8);
    float v = (lane < F_IN) ? acc[hh] / (zh + 1e-16f) : 0.f;
    unsigned short h2, l2;
    split_one(v, h2, l2);
    outHi[(size_t)d * WIDTH + hh * HID + lane] = h2;
    outLo[(size_t)d * WIDTH + hh * HID + lane] = l2;
  }
}

// ---- fused SINGLE-PASS softmax + pull aggregation (H=1), fp16 gather ------
template <int M, bool ELU, bool SPLIT>
__global__ __launch_bounds__(256) void pull_agg_sm(
    const int* __restrict__ rowptr, const int* __restrict__ csrc,
    const float* __restrict__ al_s, const float* __restrict__ al_d,
    const __half* __restrict__ h16, const float* __restrict__ bias,
    float* __restrict__ out, unsigned short* __restrict__ outHi,
    unsigned short* __restrict__ outLo) {
  constexpr int EPL = (M + 63) / 64;
  const int w = threadIdx.x >> 6;
  const int lane = threadIdx.x & 63;
  const int d = blockIdx.x * 4 + w;
  if (d >= NN) return;
  const int r0 = rowptr[d], r1 = rowptr[d + 1];
  const float ald = al_d[d];
  float m = al_s[d] + ald;                 // self-loop logit as softmax shift
  m = (m > 0.f) ? m : 0.2f * m;

  const int base = lane * EPL;
  float acc[EPL];
  #pragma unroll
  for (int j = 0; j < EPL; ++j) acc[j] = 0.f;
  float z = 0.f;

  for (int p = r0; p < r1; ++p) {
    int s = csrc[p];
    float v = al_s[s] + ald;               // broadcast load
    v = (v > 0.f) ? v : 0.2f * v;
    float a = __expf(v - m);
    z += a;
    const __half* hr = h16 + (size_t)s * M + base;
    if (M % 64 == 0 && EPL == 8) {
      uint4 raw = *(const uint4*)hr;
      float2 f0 = u2f2(raw.x), f1 = u2f2(raw.y);
      float2 f2 = u2f2(raw.z), f3 = u2f2(raw.w);
      acc[0] += f0.x * a; acc[1] += f0.y * a;
      acc[2] += f1.x * a; acc[3] += f1.y * a;
      acc[4] += f2.x * a; acc[5] += f2.y * a;
      acc[6] += f3.x * a; acc[7] += f3.y * a;
    } else {
      #pragma unroll
      for (int j = 0; j < EPL; ++j) {
        if ((M % 64 == 0) || (base + j < M))
          acc[j] += __half2float(hr[j]) * a;
      }
    }
  }
  const float iz = 1.0f / (z + 1e-16f);

  #pragma unroll
  for (int j = 0; j < EPL; ++j) {
    if ((M % 64 == 0) || (base + j < M)) {
      float v = acc[j] * iz + bias[base + j];
      if (ELU) v = (v > 0.f) ? v : (__expf(v) - 1.0f);
      if (SPLIT) {
        unsigned short hh, ll;
        split_one(v, hh, ll);
        outHi[(size_t)d * M + base + j] = hh;
        outLo[(size_t)d * M + base + j] = ll;
      } else {
        out[(size_t)d * M + base + j] = v;
      }
    }
  }
}

extern "C" void kernel_launch(void* const* d_in, const int* in_sizes, int n_in,
                              void* d_out, int out_size, void* d_ws,
                              size_t ws_size, hipStream_t stream) {
  const float* x      = (const float*)d_in[0];
  const int*   ei     = (const int*)d_in[1];
  const float* W1     = (const float*)d_in[2];
  const float* a1_src = (const float*)d_in[3];
  const float* a1_dst = (const float*)d_in[4];
  const float* b1     = (const float*)d_in[5];
  const float* W2     = (const float*)d_in[6];
  const float* a2_src = (const float*)d_in[7];
  const float* a2_dst = (const float*)d_in[8];
  const float* b2     = (const float*)d_in[9];
  const float* W3     = (const float*)d_in[10];
  const float* a3_src = (const float*)d_in[11];
  const float* a3_dst = (const float*)d_in[12];
  const float* b3     = (const float*)d_in[13];
  float* out = (float*)d_out;

  const int* esrc = ei;
  const int* edst = ei + ERAW;

  // Workspace carve-up
  unsigned short* p1Hi  = (unsigned short*)d_ws;          // NN*WIDTH
  unsigned short* p1Lo  = p1Hi + (size_t)NN * WIDTH;
  unsigned short* p2Hi  = p1Lo + (size_t)NN * WIDTH;
  unsigned short* p2Lo  = p2Hi + (size_t)NN * WIDTH;
  __half*        h16    = (__half*)(p2Lo + (size_t)NN * WIDTH);  // NN*WIDTH
  __half*        x16    = h16 + (size_t)NN * WIDTH;       // NN*F_IN
  unsigned short* w1hHi = (unsigned short*)(x16 + (size_t)NN * F_IN);
  unsigned short* w1hLo = w1hHi + (size_t)HEADS * HID * HID;
  unsigned short* w2tHi = w1hLo + (size_t)HEADS * HID * HID;  // 512*512
  unsigned short* w2tLo = w2tHi + (size_t)WIDTH * WIDTH;
  unsigned short* w3tHi = w2tLo + (size_t)WIDTH * WIDTH;  // 128*512
  unsigned short* w3tLo = w3tHi + (size_t)NCLS_P * WIDTH;
  float* al_s   = (float*)(w3tLo + (size_t)NCLS_P * WIDTH);  // NN*HEADS
  float* al_d   = al_s + (size_t)NN * HEADS;
  float* w1as   = al_d + (size_t)NN * HEADS;              // 50*8
  float* w1ad   = w1as + F_IN * HEADS;
  int* deg      = (int*)(w1ad + F_IN * HEADS);            // NN
  int* rowptr   = deg + NN;                               // NN+1 (+3 pad)
  int* cnt      = rowptr + NN + 4;                        // NN
  int* csrc     = cnt + NN;                               // ETOT

  // ---- build CSR by destination (once) ----
  hipMemsetAsync(deg, 0, (size_t)NN * sizeof(int), stream);
  hipMemsetAsync(cnt, 0, (size_t)NN * sizeof(int), stream);
  const int eblk = (ETOT + 255) / 256;
  count_deg<<<eblk, 256, 0, stream>>>(edst, deg);
  scan_deg<<<1, 256, 0, stream>>>(deg, rowptr);
  scatter_csr<<<eblk, 256, 0, stream>>>(esrc, edst, rowptr, cnt, csrc);

  // ---- weight prep + x16 (once) ----
  build_w1h_t<<<(HEADS * HID * HID + 255) / 256, 256, 0, stream>>>(W1, w1hHi,
                                                                   w1hLo);
  transpose_split<<<dim3(WIDTH / 32, WIDTH / 32), 256, 0, stream>>>(
      W2, w2tHi, w2tLo, WIDTH, WIDTH, WIDTH);
  transpose_split<<<dim3(WIDTH / 32, NCLS_P / 32), 256, 0, stream>>>(
      W3, w3tHi, w3tLo, WIDTH, NCLS, NCLS_P);
  x_to_f16<<<(NN * F_IN + 255) / 256, 256, 0, stream>>>(x, x16);

  const int nwblk = (NN + 3) / 4;

  // ---- Layer 1 (aggregate-x-first; single-pass softmax+agg; head GEMM) ----
  {
    fold_w1a<<<(2 * F_IN * HEADS + 255) / 256, 256, 0, stream>>>(
        W1, a1_src, a1_dst, w1as, w1ad);
    al1_kernel<<<nwblk, 256, 0, stream>>>(x, w1as, w1ad, al_s, al_d);
    agg_x_sm<<<nwblk, 256, 0, stream>>>(rowptr, csrc, al_s, al_d, x16, p1Hi,
                                        p1Lo);
    gemm_l1_heads<<<dim3((NN + 127) / 128, HEADS), 256, 0, stream>>>(
        p1Hi, p1Lo, w1hHi, w1hLo, p2Hi, p2Lo, b1);
  }
  // ---- Layer 2: h16 = fp16(x1 @ W2) with fused logits; agg -> P1 split ----
  {
    hipMemsetAsync(al_s, 0, (size_t)NN * sizeof(float), stream);
    hipMemsetAsync(al_d, 0, (size_t)NN * sizeof(float), stream);
    gemm_mfma_split<<<dim3(WIDTH / 128, (NN + 127) / 128), 256, 0, stream>>>(
        p2Hi, p2Lo, w2tHi, w2tLo, h16, a2_src, a2_dst, al_s, al_d, NN, WIDTH,
        WIDTH);
    pull_agg_sm<WIDTH, true, true><<<nwblk, 256, 0, stream>>>(
        rowptr, csrc, al_s, al_d, h16, b2, nullptr, p1Hi, p1Lo);
  }
  // ---- Layer 3: h16 = fp16(x2 @ W3) with fused logits; agg -> out ----
  {
    hipMemsetAsync(al_s, 0, (size_t)NN * sizeof(float), stream);
    hipMemsetAsync(al_d, 0, (size_t)NN * sizeof(float), stream);
    gemm_mfma_split<<<dim3(NCLS_P / 128, (NN + 127) / 128), 256, 0, stream>>>(
        p1Hi, p1Lo, w3tHi, w3tLo, h16, a3_src, a3_dst, al_s, al_d, NN, WIDTH,
        NCLS);
    pull_agg_sm<NCLS, false, false><<<nwblk, 256, 0, stream>>>(
        rowptr, csrc, al_s, al_d, h16, b3, out, nullptr, nullptr);
  }
}

// Round 15
// 472.117 us; speedup vs baseline: 1.0810x; 1.0810x over previous
//
#include <hip/hip_runtime.h>
#include <hip/hip_bf16.h>
#include <hip/hip_fp16.h>

// Problem constants (match reference)
#define NN     20000
#define ERAW   320000
#define ETOT   (ERAW + NN)   // 340000 with self loops
#define F_IN   50
#define HID    64
#define HEADS  8
#define WIDTH  512           // HID*HEADS
#define NCLS   121
#define NCLS_P 128           // padded cols for layer-3 MFMA GEMM

typedef __attribute__((ext_vector_type(8))) __bf16 bf16x8;
typedef __attribute__((ext_vector_type(4))) float floatx4;

// ---------------- fp32 -> bf16 split helpers --------------------------------
__device__ __forceinline__ unsigned short f32_to_bf16_rn(float f) {
  unsigned u = __float_as_uint(f);
  unsigned r = u + 0x7fffu + ((u >> 16) & 1u);
  return (unsigned short)(r >> 16);
}
__device__ __forceinline__ void split_one(float f, unsigned short& h,
                                          unsigned short& l) {
  h = f32_to_bf16_rn(f);
  float fh = __uint_as_float(((unsigned)h) << 16);
  l = f32_to_bf16_rn(f - fh);
}

__device__ __forceinline__ float2 u2f2(unsigned u) {
  __half2 hv = *reinterpret_cast<__half2*>(&u);
  return __half22float2(hv);
}

// W [K][M] fp32 -> Bt hi/lo [Mp][K] bf16 ushort (rows m>=M zero-padded)
__global__ __launch_bounds__(256) void transpose_split(
    const float* __restrict__ W, unsigned short* __restrict__ thi,
    unsigned short* __restrict__ tlo, int K, int M, int Mp) {
  __shared__ float t[32][33];
  int k0 = blockIdx.x * 32, m0 = blockIdx.y * 32;
  int tx = threadIdx.x & 31, ty = threadIdx.x >> 5;  // 32 x 8
  #pragma unroll
  for (int r = 0; r < 4; ++r) {
    int k = k0 + ty + r * 8, m = m0 + tx;
    float v = 0.f;
    if (k < K && m < M) v = W[(size_t)k * M + m];
    t[ty + r * 8][tx] = v;
  }
  __syncthreads();
  #pragma unroll
  for (int r = 0; r < 4; ++r) {
    int m = m0 + ty + r * 8, k = k0 + tx;
    if (m < Mp && k < K) {
      unsigned short h, l;
      split_one(t[tx][ty + r * 8], h, l);
      thi[(size_t)m * K + k] = h;
      tlo[(size_t)m * K + k] = l;
    }
  }
}

// Per-head W1 transposed split: w1h[hd][col(64)][k(64)], k>=50 zero.
__global__ __launch_bounds__(256) void build_w1h_t(
    const float* __restrict__ W1, unsigned short* __restrict__ thi,
    unsigned short* __restrict__ tlo) {
  int idx = blockIdx.x * blockDim.x + threadIdx.x;
  if (idx >= HEADS * HID * HID) return;
  int hd = idx >> 12, rem = idx & 4095;
  int col = rem >> 6, k = rem & 63;
  float v = (k < F_IN) ? W1[(size_t)k * WIDTH + hd * HID + col] : 0.f;
  unsigned short h, l;
  split_one(v, h, l);
  thi[idx] = h;
  tlo[idx] = l;
}

// ---- split-bf16 MFMA GEMM: C16[N,M] = fp16(A[N,K] @ B[K,M]) ----------------
// Only the fp16 copy is materialized (consumers: compute_al16 + gathers).
__global__ __launch_bounds__(256) void gemm_mfma_split(
    const unsigned short* __restrict__ Ahi, const unsigned short* __restrict__ Alo,
    const unsigned short* __restrict__ Bthi, const unsigned short* __restrict__ Btlo,
    __half* __restrict__ C16, int N, int K, int M) {
  __shared__ unsigned short sAhi[4096], sAlo[4096], sBhi[4096], sBlo[4096];
  const int tid = threadIdx.x;
  const int wave = tid >> 6, lane = tid & 63;
  const int wr = wave >> 1, wc = wave & 1;
  const int r0 = blockIdx.y * 128;
  const int c0 = blockIdx.x * 128;
  const int lkg = lane >> 4;
  const int lmn = lane & 15;

  const int skg = tid & 3;
  const int srow = tid >> 2;
  int ra0 = r0 + srow;        if (ra0 > NN - 1) ra0 = NN - 1;
  int ra1 = r0 + srow + 64;   if (ra1 > NN - 1) ra1 = NN - 1;
  const unsigned short* gAhi0 = Ahi + (size_t)ra0 * K + skg * 8;
  const unsigned short* gAhi1 = Ahi + (size_t)ra1 * K + skg * 8;
  const unsigned short* gAlo0 = Alo + (size_t)ra0 * K + skg * 8;
  const unsigned short* gAlo1 = Alo + (size_t)ra1 * K + skg * 8;
  const unsigned short* gBhi0 = Bthi + (size_t)(c0 + srow) * K + skg * 8;
  const unsigned short* gBhi1 = Bthi + (size_t)(c0 + srow + 64) * K + skg * 8;
  const unsigned short* gBlo0 = Btlo + (size_t)(c0 + srow) * K + skg * 8;
  const unsigned short* gBlo1 = Btlo + (size_t)(c0 + srow + 64) * K + skg * 8;

  floatx4 acc[4][4] = {};

  uint4 a0, a1, a2, a3, b0, b1, b2, b3;
  auto gload = [&](int kk) {
    a0 = *(const uint4*)(gAhi0 + kk);
    a1 = *(const uint4*)(gAhi1 + kk);
    a2 = *(const uint4*)(gAlo0 + kk);
    a3 = *(const uint4*)(gAlo1 + kk);
    b0 = *(const uint4*)(gBhi0 + kk);
    b1 = *(const uint4*)(gBhi1 + kk);
    b2 = *(const uint4*)(gBlo0 + kk);
    b3 = *(const uint4*)(gBlo1 + kk);
  };
  gload(0);

  const int w0 = (skg * 128 + srow) * 8;
  const int w1 = (skg * 128 + srow + 64) * 8;

  for (int k0 = 0; k0 < K; k0 += 32) {
    __syncthreads();
    *(uint4*)(sAhi + w0) = a0;
    *(uint4*)(sAhi + w1) = a1;
    *(uint4*)(sAlo + w0) = a2;
    *(uint4*)(sAlo + w1) = a3;
    *(uint4*)(sBhi + w0) = b0;
    *(uint4*)(sBhi + w1) = b1;
    *(uint4*)(sBlo + w0) = b2;
    *(uint4*)(sBlo + w1) = b3;
    __syncthreads();
    if (k0 + 32 < K) gload(k0 + 32);

    bf16x8 fAhi[4], fAlo[4], fBhi[4], fBlo[4];
    #pragma unroll
    for (int mi = 0; mi < 4; ++mi) {
      int m = wr * 64 + mi * 16 + lmn;
      fAhi[mi] = *(const bf16x8*)(sAhi + (lkg * 128 + m) * 8);
      fAlo[mi] = *(const bf16x8*)(sAlo + (lkg * 128 + m) * 8);
    }
    #pragma unroll
    for (int ni = 0; ni < 4; ++ni) {
      int n = wc * 64 + ni * 16 + lmn;
      fBhi[ni] = *(const bf16x8*)(sBhi + (lkg * 128 + n) * 8);
      fBlo[ni] = *(const bf16x8*)(sBlo + (lkg * 128 + n) * 8);
    }
    #pragma unroll
    for (int mi = 0; mi < 4; ++mi)
      #pragma unroll
      for (int ni = 0; ni < 4; ++ni) {
        acc[mi][ni] = __builtin_amdgcn_mfma_f32_16x16x32_bf16(
            fAhi[mi], fBhi[ni], acc[mi][ni], 0, 0, 0);
        acc[mi][ni] = __builtin_amdgcn_mfma_f32_16x16x32_bf16(
            fAhi[mi], fBlo[ni], acc[mi][ni], 0, 0, 0);
        acc[mi][ni] = __builtin_amdgcn_mfma_f32_16x16x32_bf16(
            fAlo[mi], fBhi[ni], acc[mi][ni], 0, 0, 0);
      }
  }

  #pragma unroll
  for (int mi = 0; mi < 4; ++mi) {
    #pragma unroll
    for (int r = 0; r < 4; ++r) {
      int grow = r0 + wr * 64 + mi * 16 + (lane >> 4) * 4 + r;
      if (grow >= N) continue;
      #pragma unroll
      for (int ni = 0; ni < 4; ++ni) {
        int gcol = c0 + wc * 64 + ni * 16 + lmn;
        if (gcol < M) C16[(size_t)grow * M + gcol] = __float2half(acc[mi][ni][r]);
      }
    }
  }
}

// ---- batched per-head L1 GEMM: C[n,hd*64+c] = elu(A[n,hd*64+:64]@W1h + b1) -
__global__ __launch_bounds__(256) void gemm_l1_heads(
    const unsigned short* __restrict__ Ahi, const unsigned short* __restrict__ Alo,
    const unsigned short* __restrict__ Bthi, const unsigned short* __restrict__ Btlo,
    unsigned short* __restrict__ outHi, unsigned short* __restrict__ outLo,
    const float* __restrict__ bias) {
  __shared__ unsigned short sAhi[8192], sAlo[8192], sBhi[4096], sBlo[4096];
  const int tid = threadIdx.x;
  const int wave = tid >> 6, lane = tid & 63;
  const int r0 = blockIdx.x * 128;
  const int hd = blockIdx.y;
  const int lkg = lane >> 4, lmn = lane & 15;

  #pragma unroll
  for (int t = 0; t < 4; ++t) {
    int cid = tid + t * 256;
    int row = cid >> 3, c = cid & 7;
    int gr = r0 + row; if (gr > NN - 1) gr = NN - 1;
    const size_t goff = (size_t)gr * WIDTH + hd * HID + c * 8;
    int loff = (((c >> 2) * 4 + (c & 3)) * 128 + row) * 8;
    *(uint4*)(sAhi + loff) = *(const uint4*)(Ahi + goff);
    *(uint4*)(sAlo + loff) = *(const uint4*)(Alo + goff);
  }
  #pragma unroll
  for (int t = 0; t < 2; ++t) {
    int cid = tid + t * 256;
    int col = cid >> 3, c = cid & 7;
    const size_t goff = (size_t)(hd * HID + col) * HID + c * 8;
    int loff = (((c >> 2) * 4 + (c & 3)) * 64 + col) * 8;
    *(uint4*)(sBhi + loff) = *(const uint4*)(Bthi + goff);
    *(uint4*)(sBlo + loff) = *(const uint4*)(Btlo + goff);
  }
  __syncthreads();

  floatx4 acc[2][4] = {};
  #pragma unroll
  for (int ks = 0; ks < 2; ++ks) {
    bf16x8 fAhi[2], fAlo[2], fBhi[4], fBlo[4];
    #pragma unroll
    for (int mi = 0; mi < 2; ++mi) {
      int m = wave * 32 + mi * 16 + lmn;
      int off = ((ks * 4 + lkg) * 128 + m) * 8;
      fAhi[mi] = *(const bf16x8*)(sAhi + off);
      fAlo[mi] = *(const bf16x8*)(sAlo + off);
    }
    #pragma unroll
    for (int ni = 0; ni < 4; ++ni) {
      int n = ni * 16 + lmn;
      int off = ((ks * 4 + lkg) * 64 + n) * 8;
      fBhi[ni] = *(const bf16x8*)(sBhi + off);
      fBlo[ni] = *(const bf16x8*)(sBlo + off);
    }
    #pragma unroll
    for (int mi = 0; mi < 2; ++mi)
      #pragma unroll
      for (int ni = 0; ni < 4; ++ni) {
        acc[mi][ni] = __builtin_amdgcn_mfma_f32_16x16x32_bf16(
            fAhi[mi], fBhi[ni], acc[mi][ni], 0, 0, 0);
        acc[mi][ni] = __builtin_amdgcn_mfma_f32_16x16x32_bf16(
            fAhi[mi], fBlo[ni], acc[mi][ni], 0, 0, 0);
        acc[mi][ni] = __builtin_amdgcn_mfma_f32_16x16x32_bf16(
            fAlo[mi], fBhi[ni], acc[mi][ni], 0, 0, 0);
      }
  }

  #pragma unroll
  for (int mi = 0; mi < 2; ++mi) {
    #pragma unroll
    for (int r = 0; r < 4; ++r) {
      int grow = r0 + wave * 32 + mi * 16 + (lane >> 4) * 4 + r;
      if (grow >= NN) continue;
      #pragma unroll
      for (int ni = 0; ni < 4; ++ni) {
        int gcol = hd * HID + ni * 16 + lmn;
        float v = acc[mi][ni][r] + bias[gcol];
        v = (v > 0.f) ? v : (__expf(v) - 1.0f);
        unsigned short hh, ll;
        split_one(v, hh, ll);
        outHi[(size_t)grow * WIDTH + gcol] = hh;
        outLo[(size_t)grow * WIDTH + gcol] = ll;
      }
    }
  }
}

// ---------------- layer-1 folded attention weights --------------------------
__global__ __launch_bounds__(256) void fold_w1a(
    const float* __restrict__ W1, const float* __restrict__ a1s,
    const float* __restrict__ a1d, float* __restrict__ w1as,
    float* __restrict__ w1ad) {
  int idx = blockIdx.x * blockDim.x + threadIdx.x;
  if (idx >= 2 * F_IN * HEADS) return;
  int which = idx >= F_IN * HEADS;
  int r = which ? idx - F_IN * HEADS : idx;
  int k = r >> 3, h = r & 7;
  const float* a = which ? a1d : a1s;
  float s = 0.f;
  for (int c = 0; c < HID; ++c) s += W1[(size_t)k * WIDTH + h * HID + c] * a[h * HID + c];
  (which ? w1ad : w1as)[r] = s;
}

// al1[n,h] = sum_k x[n,k] * w1a[k,h]   (one wave per node)
__global__ __launch_bounds__(256) void al1_kernel(
    const float* __restrict__ x, const float* __restrict__ w1as,
    const float* __restrict__ w1ad, float* __restrict__ al_s,
    float* __restrict__ al_d) {
  int n = (blockIdx.x * blockDim.x + threadIdx.x) >> 6;
  int lane = threadIdx.x & 63;
  if (n >= NN) return;
  float xv = (lane < F_IN) ? x[(size_t)n * F_IN + lane] : 0.f;
  float ws[HEADS], wd[HEADS];
  #pragma unroll
  for (int h = 0; h < HEADS; ++h) {
    ws[h] = (lane < F_IN) ? w1as[lane * HEADS + h] : 0.f;
    wd[h] = (lane < F_IN) ? w1ad[lane * HEADS + h] : 0.f;
  }
  #pragma unroll
  for (int h = 0; h < HEADS; ++h) {
    float ss = xv * ws[h], sd = xv * wd[h];
    #pragma unroll
    for (int o = 32; o; o >>= 1) {
      ss += __shfl_xor(ss, o);
      sd += __shfl_xor(sd, o);
    }
    if (lane == 0) {
      al_s[n * HEADS + h] = ss;
      al_d[n * HEADS + h] = sd;
    }
  }
}

// ---------------- per-node attention logits from fp16 h (H=1 layers) -------
template <int C>
__global__ __launch_bounds__(256) void compute_al16(
    const __half* __restrict__ h16, const float* __restrict__ a_src,
    const float* __restrict__ a_dst, float* __restrict__ al_s,
    float* __restrict__ al_d) {
  int n = (blockIdx.x * blockDim.x + threadIdx.x) >> 6;
  int lane = threadIdx.x & 63;
  if (n >= NN) return;
  const __half* hr = h16 + (size_t)n * C;
  float ss = 0.f, sd = 0.f;
  if (C % 512 == 0) {
    // lane owns cols lane*8 .. lane*8+7: one uint4 (8 halves)
    uint4 raw = *(const uint4*)(hr + lane * 8);
    float f[8];
    float2 t;
    t = u2f2(raw.x); f[0] = t.x; f[1] = t.y;
    t = u2f2(raw.y); f[2] = t.x; f[3] = t.y;
    t = u2f2(raw.z); f[4] = t.x; f[5] = t.y;
    t = u2f2(raw.w); f[6] = t.x; f[7] = t.y;
    #pragma unroll
    for (int j = 0; j < 8; ++j) {
      int c = lane * 8 + j;
      ss += f[j] * a_src[c];
      sd += f[j] * a_dst[c];
    }
  } else {
    for (int c = lane; c < C; c += 64) {
      float v = __half2float(hr[c]);
      ss += v * a_src[c];
      sd += v * a_dst[c];
    }
  }
  #pragma unroll
  for (int o = 32; o; o >>= 1) {
    ss += __shfl_xor(ss, o);
    sd += __shfl_xor(sd, o);
  }
  if (lane == 0) {
    al_s[n] = ss;
    al_d[n] = sd;
  }
}

// ---------------- CSR build (once; shared by all layers) --------------------
__global__ __launch_bounds__(256) void count_deg(
    const int* __restrict__ edst, int* __restrict__ deg) {
  int e = blockIdx.x * blockDim.x + threadIdx.x;
  if (e >= ETOT) return;
  int d = (e < ERAW) ? edst[e] : (e - ERAW);
  atomicAdd(&deg[d], 1);
}

__global__ __launch_bounds__(256) void scan_deg(
    const int* __restrict__ deg, int* __restrict__ rowptr) {
  __shared__ int part[256];
  const int t = threadIdx.x;
  const int CHUNK = (NN + 255) / 256;
  int lo = t * CHUNK, hi = min(lo + CHUNK, NN);
  int s = 0;
  for (int i = lo; i < hi; ++i) s += deg[i];
  part[t] = s;
  __syncthreads();
  for (int off = 1; off < 256; off <<= 1) {
    int v = (t >= off) ? part[t - off] : 0;
    __syncthreads();
    part[t] += v;
    __syncthreads();
  }
  int base = (t == 0) ? 0 : part[t - 1];
  for (int i = lo; i < hi; ++i) {
    rowptr[i] = base;
    base += deg[i];
  }
  if (t == 255) rowptr[NN] = part[255];
}

__global__ __launch_bounds__(256) void scatter_csr(
    const int* __restrict__ esrc, const int* __restrict__ edst,
    const int* __restrict__ rowptr, int* __restrict__ cnt,
    int* __restrict__ csrc) {
  int e = blockIdx.x * blockDim.x + threadIdx.x;
  if (e >= ETOT) return;
  int s, d;
  if (e < ERAW) { s = esrc[e]; d = edst[e]; }
  else          { s = e - ERAW; d = e - ERAW; }
  int pos = rowptr[d] + atomicAdd(&cnt[d], 1);
  csrc[pos] = s;
}

// ---- layer-1 fused SINGLE-PASS softmax+aggregate (self-loop-logit shift) --
__global__ __launch_bounds__(256) void agg_x_sm(
    const int* __restrict__ rowptr, const int* __restrict__ csrc,
    const float* __restrict__ al_s, const float* __restrict__ al_d,
    const float* __restrict__ x, unsigned short* __restrict__ outHi,
    unsigned short* __restrict__ outLo) {
  const int w = threadIdx.x >> 6, lane = threadIdx.x & 63;
  const int d = blockIdx.x * 4 + w;
  if (d >= NN) return;
  const int r0 = rowptr[d], r1 = rowptr[d + 1];
  const int mh = lane & 7;  // this lane computes alpha for head mh
  const float ald_my = al_d[d * HEADS + mh];
  float m_my = al_s[d * HEADS + mh] + ald_my;
  m_my = (m_my > 0.f) ? m_my : 0.2f * m_my;

  float z_my = 0.f;
  float acc[HEADS];
  #pragma unroll
  for (int hh = 0; hh < HEADS; ++hh) acc[hh] = 0.f;
  for (int p = r0; p < r1; ++p) {
    int s = csrc[p];
    float v = al_s[s * HEADS + mh] + ald_my;
    v = (v > 0.f) ? v : 0.2f * v;
    float a = __expf(v - m_my);
    z_my += a;
    float xv = (lane < F_IN) ? x[(size_t)s * F_IN + lane] : 0.f;
    #pragma unroll
    for (int hh = 0; hh < HEADS; ++hh) acc[hh] += __shfl(a, hh, 8) * xv;
  }
  #pragma unroll
  for (int hh = 0; hh < HEADS; ++hh) {
    float zh = __shfl(z_my, hh, 8);
    float v = (lane < F_IN) ? acc[hh] / (zh + 1e-16f) : 0.f;
    unsigned short h2, l2;
    split_one(v, h2, l2);
    outHi[(size_t)d * WIDTH + hh * HID + lane] = h2;
    outLo[(size_t)d * WIDTH + hh * HID + lane] = l2;
  }
}

// ---- fused SINGLE-PASS softmax + pull aggregation (H=1), fp16 gather ------
template <int M, bool ELU, bool SPLIT>
__global__ __launch_bounds__(256) void pull_agg_sm(
    const int* __restrict__ rowptr, const int* __restrict__ csrc,
    const float* __restrict__ al_s, const float* __restrict__ al_d,
    const __half* __restrict__ h16, const float* __restrict__ bias,
    float* __restrict__ out, unsigned short* __restrict__ outHi,
    unsigned short* __restrict__ outLo) {
  constexpr int EPL = (M + 63) / 64;
  const int w = threadIdx.x >> 6;
  const int lane = threadIdx.x & 63;
  const int d = blockIdx.x * 4 + w;
  if (d >= NN) return;
  const int r0 = rowptr[d], r1 = rowptr[d + 1];
  const float ald = al_d[d];
  float m = al_s[d] + ald;                 // self-loop logit as softmax shift
  m = (m > 0.f) ? m : 0.2f * m;

  const int base = lane * EPL;
  float acc[EPL];
  #pragma unroll
  for (int j = 0; j < EPL; ++j) acc[j] = 0.f;
  float z = 0.f;

  for (int p = r0; p < r1; ++p) {
    int s = csrc[p];
    float v = al_s[s] + ald;               // broadcast load
    v = (v > 0.f) ? v : 0.2f * v;
    float a = __expf(v - m);
    z += a;
    const __half* hr = h16 + (size_t)s * M + base;
    if (M % 64 == 0 && EPL == 8) {
      uint4 raw = *(const uint4*)hr;
      float2 f0 = u2f2(raw.x), f1 = u2f2(raw.y);
      float2 f2 = u2f2(raw.z), f3 = u2f2(raw.w);
      acc[0] += f0.x * a; acc[1] += f0.y * a;
      acc[2] += f1.x * a; acc[3] += f1.y * a;
      acc[4] += f2.x * a; acc[5] += f2.y * a;
      acc[6] += f3.x * a; acc[7] += f3.y * a;
    } else {
      #pragma unroll
      for (int j = 0; j < EPL; ++j) {
        if ((M % 64 == 0) || (base + j < M))
          acc[j] += __half2float(hr[j]) * a;
      }
    }
  }
  const float iz = 1.0f / (z + 1e-16f);

  #pragma unroll
  for (int j = 0; j < EPL; ++j) {
    if ((M % 64 == 0) || (base + j < M)) {
      float v = acc[j] * iz + bias[base + j];
      if (ELU) v = (v > 0.f) ? v : (__expf(v) - 1.0f);
      if (SPLIT) {
        unsigned short hh, ll;
        split_one(v, hh, ll);
        outHi[(size_t)d * M + base + j] = hh;
        outLo[(size_t)d * M + base + j] = ll;
      } else {
        out[(size_t)d * M + base + j] = v;
      }
    }
  }
}

extern "C" void kernel_launch(void* const* d_in, const int* in_sizes, int n_in,
                              void* d_out, int out_size, void* d_ws,
                              size_t ws_size, hipStream_t stream) {
  const float* x      = (const float*)d_in[0];
  const int*   ei     = (const int*)d_in[1];
  const float* W1     = (const float*)d_in[2];
  const float* a1_src = (const float*)d_in[3];
  const float* a1_dst = (const float*)d_in[4];
  const float* b1     = (const float*)d_in[5];
  const float* W2     = (const float*)d_in[6];
  const float* a2_src = (const float*)d_in[7];
  const float* a2_dst = (const float*)d_in[8];
  const float* b2     = (const float*)d_in[9];
  const float* W3     = (const float*)d_in[10];
  const float* a3_src = (const float*)d_in[11];
  const float* a3_dst = (const float*)d_in[12];
  const float* b3     = (const float*)d_in[13];
  float* out = (float*)d_out;

  const int* esrc = ei;
  const int* edst = ei + ERAW;

  // Workspace carve-up
  unsigned short* p1Hi  = (unsigned short*)d_ws;          // NN*WIDTH
  unsigned short* p1Lo  = p1Hi + (size_t)NN * WIDTH;
  unsigned short* p2Hi  = p1Lo + (size_t)NN * WIDTH;
  unsigned short* p2Lo  = p2Hi + (size_t)NN * WIDTH;
  __half*        h16    = (__half*)(p2Lo + (size_t)NN * WIDTH);  // NN*WIDTH
  unsigned short* w1hHi = (unsigned short*)(h16 + (size_t)NN * WIDTH);
  unsigned short* w1hLo = w1hHi + (size_t)HEADS * HID * HID;
  unsigned short* w2tHi = w1hLo + (size_t)HEADS * HID * HID;  // 512*512
  unsigned short* w2tLo = w2tHi + (size_t)WIDTH * WIDTH;
  unsigned short* w3tHi = w2tLo + (size_t)WIDTH * WIDTH;  // 128*512
  unsigned short* w3tLo = w3tHi + (size_t)NCLS_P * WIDTH;
  float* al_s   = (float*)(w3tLo + (size_t)NCLS_P * WIDTH);  // NN*HEADS
  float* al_d   = al_s + (size_t)NN * HEADS;
  float* w1as   = al_d + (size_t)NN * HEADS;              // 50*8
  float* w1ad   = w1as + F_IN * HEADS;
  int* deg      = (int*)(w1ad + F_IN * HEADS);            // NN
  int* rowptr   = deg + NN;                               // NN+1 (+3 pad)
  int* cnt      = rowptr + NN + 4;                        // NN
  int* csrc     = cnt + NN;                               // ETOT

  // ---- build CSR by destination (once) ----
  hipMemsetAsync(deg, 0, (size_t)NN * sizeof(int), stream);
  hipMemsetAsync(cnt, 0, (size_t)NN * sizeof(int), stream);
  const int eblk = (ETOT + 255) / 256;
  count_deg<<<eblk, 256, 0, stream>>>(edst, deg);
  scan_deg<<<1, 256, 0, stream>>>(deg, rowptr);
  scatter_csr<<<eblk, 256, 0, stream>>>(esrc, edst, rowptr, cnt, csrc);

  // ---- weight prep (once) ----
  build_w1h_t<<<(HEADS * HID * HID + 255) / 256, 256, 0, stream>>>(W1, w1hHi,
                                                                   w1hLo);
  transpose_split<<<dim3(WIDTH / 32, WIDTH / 32), 256, 0, stream>>>(
      W2, w2tHi, w2tLo, WIDTH, WIDTH, WIDTH);
  transpose_split<<<dim3(WIDTH / 32, NCLS_P / 32), 256, 0, stream>>>(
      W3, w3tHi, w3tLo, WIDTH, NCLS, NCLS_P);

  const int nwblk = (NN + 3) / 4;

  // ---- Layer 1 (aggregate-x-first; single-pass softmax+agg; head GEMM) ----
  {
    fold_w1a<<<(2 * F_IN * HEADS + 255) / 256, 256, 0, stream>>>(
        W1, a1_src, a1_dst, w1as, w1ad);
    al1_kernel<<<nwblk, 256, 0, stream>>>(x, w1as, w1ad, al_s, al_d);
    agg_x_sm<<<nwblk, 256, 0, stream>>>(rowptr, csrc, al_s, al_d, x, p1Hi,
                                        p1Lo);
    gemm_l1_heads<<<dim3((NN + 127) / 128, HEADS), 256, 0, stream>>>(
        p1Hi, p1Lo, w1hHi, w1hLo, p2Hi, p2Lo, b1);
  }
  // ---- Layer 2: h16 = fp16(x1 @ W2); al from h16; softmax-agg -> P1 split -
  {
    gemm_mfma_split<<<dim3(WIDTH / 128, (NN + 127) / 128), 256, 0, stream>>>(
        p2Hi, p2Lo, w2tHi, w2tLo, h16, NN, WIDTH, WIDTH);
    compute_al16<WIDTH><<<nwblk, 256, 0, stream>>>(h16, a2_src, a2_dst, al_s,
                                                   al_d);
    pull_agg_sm<WIDTH, true, true><<<nwblk, 256, 0, stream>>>(
        rowptr, csrc, al_s, al_d, h16, b2, nullptr, p1Hi, p1Lo);
  }
  // ---- Layer 3: h16 = fp16(x2 @ W3); al from h16; softmax-agg -> out ------
  {
    gemm_mfma_split<<<dim3(NCLS_P / 128, (NN + 127) / 128), 256, 0, stream>>>(
        p1Hi, p1Lo, w3tHi, w3tLo, h16, NN, WIDTH, NCLS);
    compute_al16<NCLS><<<nwblk, 256, 0, stream>>>(h16, a3_src, a3_dst, al_s,
                                                  al_d);
    pull_agg_sm<NCLS, false, false><<<nwblk, 256, 0, stream>>>(
        rowptr, csrc, al_s, al_d, h16, b3, out, nullptr, nullptr);
  }
}

// Round 16
// 448.757 us; speedup vs baseline: 1.1373x; 1.0521x over previous
//
#include <hip/hip_runtime.h>
#include <hip/hip_bf16.h>
#include <hip/hip_fp16.h>

// Problem constants (match reference)
#define NN     20000
#define ERAW   320000
#define ETOT   (ERAW + NN)   // 340000 with self loops
#define F_IN   50
#define HID    64
#define HEADS  8
#define WIDTH  512           // HID*HEADS
#define NCLS   121
#define NCLS_P 128           // padded cols for layer-3 MFMA GEMM + h16 stride

typedef __attribute__((ext_vector_type(8))) __bf16 bf16x8;
typedef __attribute__((ext_vector_type(4))) float floatx4;

// ---------------- fp32 -> bf16 split helpers --------------------------------
__device__ __forceinline__ unsigned short f32_to_bf16_rn(float f) {
  unsigned u = __float_as_uint(f);
  unsigned r = u + 0x7fffu + ((u >> 16) & 1u);
  return (unsigned short)(r >> 16);
}
__device__ __forceinline__ void split_one(float f, unsigned short& h,
                                          unsigned short& l) {
  h = f32_to_bf16_rn(f);
  float fh = __uint_as_float(((unsigned)h) << 16);
  l = f32_to_bf16_rn(f - fh);
}

__device__ __forceinline__ float2 u2f2(unsigned u) {
  __half2 hv = *reinterpret_cast<__half2*>(&u);
  return __half22float2(hv);
}

// ---- ONE weight-prep kernel (replaces 4 dispatches) ------------------------
// blocks [0,256):   W2 transpose+split (16x16 tiles of 32)
// blocks [256,320): W3 transpose+split (16x4)
// blocks [320,448): w1h per-head W1 split
// block  448:       fold_w1a
#define PW_BLOCKS 449
__global__ __launch_bounds__(256) void prep_weights(
    const float* __restrict__ W1, const float* __restrict__ W2,
    const float* __restrict__ W3, const float* __restrict__ a1s,
    const float* __restrict__ a1d, unsigned short* __restrict__ w1hHi,
    unsigned short* __restrict__ w1hLo, unsigned short* __restrict__ w2tHi,
    unsigned short* __restrict__ w2tLo, unsigned short* __restrict__ w3tHi,
    unsigned short* __restrict__ w3tLo, float* __restrict__ w1as,
    float* __restrict__ w1ad) {
  __shared__ float t[32][33];
  const int b = blockIdx.x;
  if (b < 320) {
    const float* W;
    unsigned short *thi, *tlo;
    int M, Mp, bx, by;
    const int K = WIDTH;
    if (b < 256) {
      W = W2; thi = w2tHi; tlo = w2tLo; M = WIDTH; Mp = WIDTH;
      bx = b & 15; by = b >> 4;
    } else {
      int bb = b - 256;
      W = W3; thi = w3tHi; tlo = w3tLo; M = NCLS; Mp = NCLS_P;
      bx = bb & 15; by = bb >> 4;
    }
    int k0 = bx * 32, m0 = by * 32;
    int tx = threadIdx.x & 31, ty = threadIdx.x >> 5;  // 32 x 8
    #pragma unroll
    for (int r = 0; r < 4; ++r) {
      int k = k0 + ty + r * 8, m = m0 + tx;
      float v = 0.f;
      if (k < K && m < M) v = W[(size_t)k * M + m];
      t[ty + r * 8][tx] = v;
    }
    __syncthreads();
    #pragma unroll
    for (int r = 0; r < 4; ++r) {
      int m = m0 + ty + r * 8, k = k0 + tx;
      if (m < Mp && k < K) {
        unsigned short h, l;
        split_one(t[tx][ty + r * 8], h, l);
        thi[(size_t)m * K + k] = h;
        tlo[(size_t)m * K + k] = l;
      }
    }
  } else if (b < 448) {
    int idx = (b - 320) * 256 + threadIdx.x;
    if (idx < HEADS * HID * HID) {
      int hd = idx >> 12, rem = idx & 4095;
      int col = rem >> 6, k = rem & 63;
      float v = (k < F_IN) ? W1[(size_t)k * WIDTH + hd * HID + col] : 0.f;
      unsigned short h, l;
      split_one(v, h, l);
      w1hHi[idx] = h;
      w1hLo[idx] = l;
    }
  } else {
    for (int idx = threadIdx.x; idx < 2 * F_IN * HEADS; idx += 256) {
      int which = idx >= F_IN * HEADS;
      int r = which ? idx - F_IN * HEADS : idx;
      int k = r >> 3, h = r & 7;
      const float* a = which ? a1d : a1s;
      float s = 0.f;
      for (int c = 0; c < HID; ++c)
        s += W1[(size_t)k * WIDTH + h * HID + c] * a[h * HID + c];
      (which ? w1ad : w1as)[r] = s;
    }
  }
}

// ---- split-bf16 MFMA GEMM: C16[N,Mp] = fp16(A[N,K] @ B[K,M]), zero-padded --
__global__ __launch_bounds__(256) void gemm_mfma_split(
    const unsigned short* __restrict__ Ahi, const unsigned short* __restrict__ Alo,
    const unsigned short* __restrict__ Bthi, const unsigned short* __restrict__ Btlo,
    __half* __restrict__ C16, int N, int K, int M, int Mp) {
  __shared__ unsigned short sAhi[4096], sAlo[4096], sBhi[4096], sBlo[4096];
  const int tid = threadIdx.x;
  const int wave = tid >> 6, lane = tid & 63;
  const int wr = wave >> 1, wc = wave & 1;
  const int r0 = blockIdx.y * 128;
  const int c0 = blockIdx.x * 128;
  const int lkg = lane >> 4;
  const int lmn = lane & 15;

  const int skg = tid & 3;
  const int srow = tid >> 2;
  int ra0 = r0 + srow;        if (ra0 > NN - 1) ra0 = NN - 1;
  int ra1 = r0 + srow + 64;   if (ra1 > NN - 1) ra1 = NN - 1;
  const unsigned short* gAhi0 = Ahi + (size_t)ra0 * K + skg * 8;
  const unsigned short* gAhi1 = Ahi + (size_t)ra1 * K + skg * 8;
  const unsigned short* gAlo0 = Alo + (size_t)ra0 * K + skg * 8;
  const unsigned short* gAlo1 = Alo + (size_t)ra1 * K + skg * 8;
  const unsigned short* gBhi0 = Bthi + (size_t)(c0 + srow) * K + skg * 8;
  const unsigned short* gBhi1 = Bthi + (size_t)(c0 + srow + 64) * K + skg * 8;
  const unsigned short* gBlo0 = Btlo + (size_t)(c0 + srow) * K + skg * 8;
  const unsigned short* gBlo1 = Btlo + (size_t)(c0 + srow + 64) * K + skg * 8;

  floatx4 acc[4][4] = {};

  uint4 a0, a1, a2, a3, b0, b1, b2, b3;
  auto gload = [&](int kk) {
    a0 = *(const uint4*)(gAhi0 + kk);
    a1 = *(const uint4*)(gAhi1 + kk);
    a2 = *(const uint4*)(gAlo0 + kk);
    a3 = *(const uint4*)(gAlo1 + kk);
    b0 = *(const uint4*)(gBhi0 + kk);
    b1 = *(const uint4*)(gBhi1 + kk);
    b2 = *(const uint4*)(gBlo0 + kk);
    b3 = *(const uint4*)(gBlo1 + kk);
  };
  gload(0);

  const int w0 = (skg * 128 + srow) * 8;
  const int w1 = (skg * 128 + srow + 64) * 8;

  for (int k0 = 0; k0 < K; k0 += 32) {
    __syncthreads();
    *(uint4*)(sAhi + w0) = a0;
    *(uint4*)(sAhi + w1) = a1;
    *(uint4*)(sAlo + w0) = a2;
    *(uint4*)(sAlo + w1) = a3;
    *(uint4*)(sBhi + w0) = b0;
    *(uint4*)(sBhi + w1) = b1;
    *(uint4*)(sBlo + w0) = b2;
    *(uint4*)(sBlo + w1) = b3;
    __syncthreads();
    if (k0 + 32 < K) gload(k0 + 32);

    bf16x8 fAhi[4], fAlo[4], fBhi[4], fBlo[4];
    #pragma unroll
    for (int mi = 0; mi < 4; ++mi) {
      int m = wr * 64 + mi * 16 + lmn;
      fAhi[mi] = *(const bf16x8*)(sAhi + (lkg * 128 + m) * 8);
      fAlo[mi] = *(const bf16x8*)(sAlo + (lkg * 128 + m) * 8);
    }
    #pragma unroll
    for (int ni = 0; ni < 4; ++ni) {
      int n = wc * 64 + ni * 16 + lmn;
      fBhi[ni] = *(const bf16x8*)(sBhi + (lkg * 128 + n) * 8);
      fBlo[ni] = *(const bf16x8*)(sBlo + (lkg * 128 + n) * 8);
    }
    #pragma unroll
    for (int mi = 0; mi < 4; ++mi)
      #pragma unroll
      for (int ni = 0; ni < 4; ++ni) {
        acc[mi][ni] = __builtin_amdgcn_mfma_f32_16x16x32_bf16(
            fAhi[mi], fBhi[ni], acc[mi][ni], 0, 0, 0);
        acc[mi][ni] = __builtin_amdgcn_mfma_f32_16x16x32_bf16(
            fAhi[mi], fBlo[ni], acc[mi][ni], 0, 0, 0);
        acc[mi][ni] = __builtin_amdgcn_mfma_f32_16x16x32_bf16(
            fAlo[mi], fBhi[ni], acc[mi][ni], 0, 0, 0);
      }
  }

  #pragma unroll
  for (int mi = 0; mi < 4; ++mi) {
    #pragma unroll
    for (int r = 0; r < 4; ++r) {
      int grow = r0 + wr * 64 + mi * 16 + (lane >> 4) * 4 + r;
      if (grow >= N) continue;
      #pragma unroll
      for (int ni = 0; ni < 4; ++ni) {
        int gcol = c0 + wc * 64 + ni * 16 + lmn;
        if (gcol < Mp) {
          float v = (gcol < M) ? acc[mi][ni][r] : 0.f;
          C16[(size_t)grow * Mp + gcol] = __float2half(v);
        }
      }
    }
  }
}

// ---- batched per-head L1 GEMM: C[n,hd*64+c] = elu(A[n,hd*64+:64]@W1h + b1) -
__global__ __launch_bounds__(256) void gemm_l1_heads(
    const unsigned short* __restrict__ Ahi, const unsigned short* __restrict__ Alo,
    const unsigned short* __restrict__ Bthi, const unsigned short* __restrict__ Btlo,
    unsigned short* __restrict__ outHi, unsigned short* __restrict__ outLo,
    const float* __restrict__ bias) {
  __shared__ unsigned short sAhi[8192], sAlo[8192], sBhi[4096], sBlo[4096];
  const int tid = threadIdx.x;
  const int wave = tid >> 6, lane = tid & 63;
  const int r0 = blockIdx.x * 128;
  const int hd = blockIdx.y;
  const int lkg = lane >> 4, lmn = lane & 15;

  #pragma unroll
  for (int t = 0; t < 4; ++t) {
    int cid = tid + t * 256;
    int row = cid >> 3, c = cid & 7;
    int gr = r0 + row; if (gr > NN - 1) gr = NN - 1;
    const size_t goff = (size_t)gr * WIDTH + hd * HID + c * 8;
    int loff = (((c >> 2) * 4 + (c & 3)) * 128 + row) * 8;
    *(uint4*)(sAhi + loff) = *(const uint4*)(Ahi + goff);
    *(uint4*)(sAlo + loff) = *(const uint4*)(Alo + goff);
  }
  #pragma unroll
  for (int t = 0; t < 2; ++t) {
    int cid = tid + t * 256;
    int col = cid >> 3, c = cid & 7;
    const size_t goff = (size_t)(hd * HID + col) * HID + c * 8;
    int loff = (((c >> 2) * 4 + (c & 3)) * 64 + col) * 8;
    *(uint4*)(sBhi + loff) = *(const uint4*)(Bthi + goff);
    *(uint4*)(sBlo + loff) = *(const uint4*)(Btlo + goff);
  }
  __syncthreads();

  floatx4 acc[2][4] = {};
  #pragma unroll
  for (int ks = 0; ks < 2; ++ks) {
    bf16x8 fAhi[2], fAlo[2], fBhi[4], fBlo[4];
    #pragma unroll
    for (int mi = 0; mi < 2; ++mi) {
      int m = wave * 32 + mi * 16 + lmn;
      int off = ((ks * 4 + lkg) * 128 + m) * 8;
      fAhi[mi] = *(const bf16x8*)(sAhi + off);
      fAlo[mi] = *(const bf16x8*)(sAlo + off);
    }
    #pragma unroll
    for (int ni = 0; ni < 4; ++ni) {
      int n = ni * 16 + lmn;
      int off = ((ks * 4 + lkg) * 64 + n) * 8;
      fBhi[ni] = *(const bf16x8*)(sBhi + off);
      fBlo[ni] = *(const bf16x8*)(sBlo + off);
    }
    #pragma unroll
    for (int mi = 0; mi < 2; ++mi)
      #pragma unroll
      for (int ni = 0; ni < 4; ++ni) {
        acc[mi][ni] = __builtin_amdgcn_mfma_f32_16x16x32_bf16(
            fAhi[mi], fBhi[ni], acc[mi][ni], 0, 0, 0);
        acc[mi][ni] = __builtin_amdgcn_mfma_f32_16x16x32_bf16(
            fAhi[mi], fBlo[ni], acc[mi][ni], 0, 0, 0);
        acc[mi][ni] = __builtin_amdgcn_mfma_f32_16x16x32_bf16(
            fAlo[mi], fBhi[ni], acc[mi][ni], 0, 0, 0);
      }
  }

  #pragma unroll
  for (int mi = 0; mi < 2; ++mi) {
    #pragma unroll
    for (int r = 0; r < 4; ++r) {
      int grow = r0 + wave * 32 + mi * 16 + (lane >> 4) * 4 + r;
      if (grow >= NN) continue;
      #pragma unroll
      for (int ni = 0; ni < 4; ++ni) {
        int gcol = hd * HID + ni * 16 + lmn;
        float v = acc[mi][ni][r] + bias[gcol];
        v = (v > 0.f) ? v : (__expf(v) - 1.0f);
        unsigned short hh, ll;
        split_one(v, hh, ll);
        outHi[(size_t)grow * WIDTH + gcol] = hh;
        outLo[(size_t)grow * WIDTH + gcol] = ll;
      }
    }
  }
}

// al1[n,h] = sum_k x[n,k] * w1a[k,h]   (one wave per node)
__global__ __launch_bounds__(256) void al1_kernel(
    const float* __restrict__ x, const float* __restrict__ w1as,
    const float* __restrict__ w1ad, float* __restrict__ al_s,
    float* __restrict__ al_d) {
  int n = (blockIdx.x * blockDim.x + threadIdx.x) >> 6;
  int lane = threadIdx.x & 63;
  if (n >= NN) return;
  float xv = (lane < F_IN) ? x[(size_t)n * F_IN + lane] : 0.f;
  float ws[HEADS], wd[HEADS];
  #pragma unroll
  for (int h = 0; h < HEADS; ++h) {
    ws[h] = (lane < F_IN) ? w1as[lane * HEADS + h] : 0.f;
    wd[h] = (lane < F_IN) ? w1ad[lane * HEADS + h] : 0.f;
  }
  #pragma unroll
  for (int h = 0; h < HEADS; ++h) {
    float ss = xv * ws[h], sd = xv * wd[h];
    #pragma unroll
    for (int o = 32; o; o >>= 1) {
      ss += __shfl_xor(ss, o);
      sd += __shfl_xor(sd, o);
    }
    if (lane == 0) {
      al_s[n * HEADS + h] = ss;
      al_d[n * HEADS + h] = sd;
    }
  }
}

// ---------------- per-node attention logits from fp16 h (H=1 layers) -------
// C = logical cols, CS = storage stride
template <int C, int CS>
__global__ __launch_bounds__(256) void compute_al16(
    const __half* __restrict__ h16, const float* __restrict__ a_src,
    const float* __restrict__ a_dst, float* __restrict__ al_s,
    float* __restrict__ al_d) {
  int n = (blockIdx.x * blockDim.x + threadIdx.x) >> 6;
  int lane = threadIdx.x & 63;
  if (n >= NN) return;
  const __half* hr = h16 + (size_t)n * CS;
  float ss = 0.f, sd = 0.f;
  if (C % 512 == 0) {
    uint4 raw = *(const uint4*)(hr + lane * 8);
    float f[8];
    float2 t;
    t = u2f2(raw.x); f[0] = t.x; f[1] = t.y;
    t = u2f2(raw.y); f[2] = t.x; f[3] = t.y;
    t = u2f2(raw.z); f[4] = t.x; f[5] = t.y;
    t = u2f2(raw.w); f[6] = t.x; f[7] = t.y;
    #pragma unroll
    for (int j = 0; j < 8; ++j) {
      int c = lane * 8 + j;
      ss += f[j] * a_src[c];
      sd += f[j] * a_dst[c];
    }
  } else {
    for (int c = lane; c < C; c += 64) {
      float v = __half2float(hr[c]);
      ss += v * a_src[c];
      sd += v * a_dst[c];
    }
  }
  #pragma unroll
  for (int o = 32; o; o >>= 1) {
    ss += __shfl_xor(ss, o);
    sd += __shfl_xor(sd, o);
  }
  if (lane == 0) {
    al_s[n] = ss;
    al_d[n] = sd;
  }
}

// ---------------- CSR build (once; shared by all layers) --------------------
__global__ __launch_bounds__(256) void count_deg(
    const int* __restrict__ edst, int* __restrict__ deg) {
  int e = blockIdx.x * blockDim.x + threadIdx.x;
  if (e >= ETOT) return;
  int d = (e < ERAW) ? edst[e] : (e - ERAW);
  atomicAdd(&deg[d], 1);
}

__global__ __launch_bounds__(256) void scan_deg(
    const int* __restrict__ deg, int* __restrict__ rowptr) {
  __shared__ int part[256];
  const int t = threadIdx.x;
  const int CHUNK = (NN + 255) / 256;
  int lo = t * CHUNK, hi = min(lo + CHUNK, NN);
  int s = 0;
  for (int i = lo; i < hi; ++i) s += deg[i];
  part[t] = s;
  __syncthreads();
  for (int off = 1; off < 256; off <<= 1) {
    int v = (t >= off) ? part[t - off] : 0;
    __syncthreads();
    part[t] += v;
    __syncthreads();
  }
  int base = (t == 0) ? 0 : part[t - 1];
  for (int i = lo; i < hi; ++i) {
    rowptr[i] = base;
    base += deg[i];
  }
  if (t == 255) rowptr[NN] = part[255];
}

__global__ __launch_bounds__(256) void scatter_csr(
    const int* __restrict__ esrc, const int* __restrict__ edst,
    const int* __restrict__ rowptr, int* __restrict__ cnt,
    int* __restrict__ csrc) {
  int e = blockIdx.x * blockDim.x + threadIdx.x;
  if (e >= ETOT) return;
  int s, d;
  if (e < ERAW) { s = esrc[e]; d = edst[e]; }
  else          { s = e - ERAW; d = e - ERAW; }
  int pos = rowptr[d] + atomicAdd(&cnt[d], 1);
  csrc[pos] = s;
}

// ---- layer-1 fused SINGLE-PASS softmax+aggregate (self-loop-logit shift) --
__global__ __launch_bounds__(256) void agg_x_sm(
    const int* __restrict__ rowptr, const int* __restrict__ csrc,
    const float* __restrict__ al_s, const float* __restrict__ al_d,
    const float* __restrict__ x, unsigned short* __restrict__ outHi,
    unsigned short* __restrict__ outLo) {
  const int w = threadIdx.x >> 6, lane = threadIdx.x & 63;
  const int d = blockIdx.x * 4 + w;
  if (d >= NN) return;
  const int r0 = rowptr[d], r1 = rowptr[d + 1];
  const int mh = lane & 7;
  const float ald_my = al_d[d * HEADS + mh];
  float m_my = al_s[d * HEADS + mh] + ald_my;
  m_my = (m_my > 0.f) ? m_my : 0.2f * m_my;

  float z_my = 0.f;
  float acc[HEADS];
  #pragma unroll
  for (int hh = 0; hh < HEADS; ++hh) acc[hh] = 0.f;
  for (int p = r0; p < r1; ++p) {
    int s = csrc[p];
    float v = al_s[s * HEADS + mh] + ald_my;
    v = (v > 0.f) ? v : 0.2f * v;
    float a = __expf(v - m_my);
    z_my += a;
    float xv = (lane < F_IN) ? x[(size_t)s * F_IN + lane] : 0.f;
    #pragma unroll
    for (int hh = 0; hh < HEADS; ++hh) acc[hh] += __shfl(a, hh, 8) * xv;
  }
  #pragma unroll
  for (int hh = 0; hh < HEADS; ++hh) {
    float zh = __shfl(z_my, hh, 8);
    float v = (lane < F_IN) ? acc[hh] / (zh + 1e-16f) : 0.f;
    unsigned short h2, l2;
    split_one(v, h2, l2);
    outHi[(size_t)d * WIDTH + hh * HID + lane] = h2;
    outLo[(size_t)d * WIDTH + hh * HID + lane] = l2;
  }
}

// ---- fused SINGLE-PASS softmax + pull aggregation (H=1), fp16 gather ------
// M = logical cols, MS = storage stride (padded; lanes cover all MS cols).
template <int M, int MS, bool ELU, bool SPLIT>
__global__ __launch_bounds__(256) void pull_agg_sm(
    const int* __restrict__ rowptr, const int* __restrict__ csrc,
    const float* __restrict__ al_s, const float* __restrict__ al_d,
    const __half* __restrict__ h16, const float* __restrict__ bias,
    float* __restrict__ out, unsigned short* __restrict__ outHi,
    unsigned short* __restrict__ outLo) {
  constexpr int EPL = MS / 64;
  const int w = threadIdx.x >> 6;
  const int lane = threadIdx.x & 63;
  const int d = blockIdx.x * 4 + w;
  if (d >= NN) return;
  const int r0 = rowptr[d], r1 = rowptr[d + 1];
  const float ald = al_d[d];
  float m = al_s[d] + ald;                 // self-loop logit as softmax shift
  m = (m > 0.f) ? m : 0.2f * m;

  const int base = lane * EPL;
  float acc[EPL];
  #pragma unroll
  for (int j = 0; j < EPL; ++j) acc[j] = 0.f;
  float z = 0.f;

  for (int p = r0; p < r1; ++p) {
    int s = csrc[p];
    float v = al_s[s] + ald;               // broadcast load
    v = (v > 0.f) ? v : 0.2f * v;
    float a = __expf(v - m);
    z += a;
    const __half* hr = h16 + (size_t)s * MS + base;
    if (EPL == 8) {
      uint4 raw = *(const uint4*)hr;
      float2 f0 = u2f2(raw.x), f1 = u2f2(raw.y);
      float2 f2 = u2f2(raw.z), f3 = u2f2(raw.w);
      acc[0] += f0.x * a; acc[1] += f0.y * a;
      acc[2] += f1.x * a; acc[3] += f1.y * a;
      acc[4] += f2.x * a; acc[5] += f2.y * a;
      acc[6] += f3.x * a; acc[7] += f3.y * a;
    } else if (EPL == 2) {
      unsigned raw = *(const unsigned*)hr;   // aligned: base*2 bytes, 4B
      float2 f0 = u2f2(raw);
      acc[0] += f0.x * a;
      acc[1] += f0.y * a;
    } else {
      #pragma unroll
      for (int j = 0; j < EPL; ++j) acc[j] += __half2float(hr[j]) * a;
    }
  }
  const float iz = 1.0f / (z + 1e-16f);

  #pragma unroll
  for (int j = 0; j < EPL; ++j) {
    if ((M == MS) || (base + j < M)) {
      float v = acc[j] * iz + bias[base + j];
      if (ELU) v = (v > 0.f) ? v : (__expf(v) - 1.0f);
      if (SPLIT) {
        unsigned short hh, ll;
        split_one(v, hh, ll);
        outHi[(size_t)d * M + base + j] = hh;
        outLo[(size_t)d * M + base + j] = ll;
      } else {
        out[(size_t)d * M + base + j] = v;
      }
    }
  }
}

extern "C" void kernel_launch(void* const* d_in, const int* in_sizes, int n_in,
                              void* d_out, int out_size, void* d_ws,
                              size_t ws_size, hipStream_t stream) {
  const float* x      = (const float*)d_in[0];
  const int*   ei     = (const int*)d_in[1];
  const float* W1     = (const float*)d_in[2];
  const float* a1_src = (const float*)d_in[3];
  const float* a1_dst = (const float*)d_in[4];
  const float* b1     = (const float*)d_in[5];
  const float* W2     = (const float*)d_in[6];
  const float* a2_src = (const float*)d_in[7];
  const float* a2_dst = (const float*)d_in[8];
  const float* b2     = (const float*)d_in[9];
  const float* W3     = (const float*)d_in[10];
  const float* a3_src = (const float*)d_in[11];
  const float* a3_dst = (const float*)d_in[12];
  const float* b3     = (const float*)d_in[13];
  float* out = (float*)d_out;

  const int* esrc = ei;
  const int* edst = ei + ERAW;

  // Workspace carve-up
  unsigned short* p1Hi  = (unsigned short*)d_ws;          // NN*WIDTH
  unsigned short* p1Lo  = p1Hi + (size_t)NN * WIDTH;
  unsigned short* p2Hi  = p1Lo + (size_t)NN * WIDTH;
  unsigned short* p2Lo  = p2Hi + (size_t)NN * WIDTH;
  __half*        h16    = (__half*)(p2Lo + (size_t)NN * WIDTH);  // NN*WIDTH
  unsigned short* w1hHi = (unsigned short*)(h16 + (size_t)NN * WIDTH);
  unsigned short* w1hLo = w1hHi + (size_t)HEADS * HID * HID;
  unsigned short* w2tHi = w1hLo + (size_t)HEADS * HID * HID;  // 512*512
  unsigned short* w2tLo = w2tHi + (size_t)WIDTH * WIDTH;
  unsigned short* w3tHi = w2tLo + (size_t)WIDTH * WIDTH;  // 128*512
  unsigned short* w3tLo = w3tHi + (size_t)NCLS_P * WIDTH;
  float* al_s   = (float*)(w3tLo + (size_t)NCLS_P * WIDTH);  // NN*HEADS
  float* al_d   = al_s + (size_t)NN * HEADS;
  float* w1as   = al_d + (size_t)NN * HEADS;              // 50*8
  float* w1ad   = w1as + F_IN * HEADS;
  int* deg      = (int*)(w1ad + F_IN * HEADS);            // NN
  int* cnt      = deg + NN;                               // NN  (adjacent!)
  int* rowptr   = cnt + NN;                               // NN+1 (+3 pad)
  int* csrc     = rowptr + NN + 4;                        // ETOT

  // ---- build CSR by destination (once): ONE memset covers deg+cnt ----
  hipMemsetAsync(deg, 0, (size_t)(2 * NN) * sizeof(int), stream);
  const int eblk = (ETOT + 255) / 256;
  count_deg<<<eblk, 256, 0, stream>>>(edst, deg);
  scan_deg<<<1, 256, 0, stream>>>(deg, rowptr);
  scatter_csr<<<eblk, 256, 0, stream>>>(esrc, edst, rowptr, cnt, csrc);

  // ---- ALL weight prep in one dispatch ----
  prep_weights<<<PW_BLOCKS, 256, 0, stream>>>(
      W1, W2, W3, a1_src, a1_dst, w1hHi, w1hLo, w2tHi, w2tLo, w3tHi, w3tLo,
      w1as, w1ad);

  const int nwblk = (NN + 3) / 4;

  // ---- Layer 1 (aggregate-x-first; single-pass softmax+agg; head GEMM) ----
  al1_kernel<<<nwblk, 256, 0, stream>>>(x, w1as, w1ad, al_s, al_d);
  agg_x_sm<<<nwblk, 256, 0, stream>>>(rowptr, csrc, al_s, al_d, x, p1Hi,
                                      p1Lo);
  gemm_l1_heads<<<dim3((NN + 127) / 128, HEADS), 256, 0, stream>>>(
      p1Hi, p1Lo, w1hHi, w1hLo, p2Hi, p2Lo, b1);

  // ---- Layer 2: h16 = fp16(x1 @ W2); al from h16; softmax-agg -> P1 split -
  gemm_mfma_split<<<dim3(WIDTH / 128, (NN + 127) / 128), 256, 0, stream>>>(
      p2Hi, p2Lo, w2tHi, w2tLo, h16, NN, WIDTH, WIDTH, WIDTH);
  compute_al16<WIDTH, WIDTH><<<nwblk, 256, 0, stream>>>(h16, a2_src, a2_dst,
                                                        al_s, al_d);
  pull_agg_sm<WIDTH, WIDTH, true, true><<<nwblk, 256, 0, stream>>>(
      rowptr, csrc, al_s, al_d, h16, b2, nullptr, p1Hi, p1Lo);

  // ---- Layer 3: h16 = fp16(x2 @ W3) padded to 128; al; agg -> out ---------
  gemm_mfma_split<<<dim3(NCLS_P / 128, (NN + 127) / 128), 256, 0, stream>>>(
      p1Hi, p1Lo, w3tHi, w3tLo, h16, NN, WIDTH, NCLS, NCLS_P);
  compute_al16<NCLS, NCLS_P><<<nwblk, 256, 0, stream>>>(h16, a3_src, a3_dst,
                                                        al_s, al_d);
  pull_agg_sm<NCLS, NCLS_P, false, false><<<nwblk, 256, 0, stream>>>(
      rowptr, csrc, al_s, al_d, h16, b3, out, nullptr, nullptr);
}